// Round 1
// baseline (358.272 us; speedup 1.0000x reference)
//
#include <hip/hip_runtime.h>

// TemplatePointwiseAttention, MI355X/gfx950.
// Refactor: fold Wq@Wk^T and Wv@Wo per head (T=4 keys, softmax between two
// linear maps) -> two bf16 MFMA GEMMs (K=128, K=256) + tiny 4-way softmax.
// 68k MACs/pair instead of 199k; fused, G/S intermediates stay in LDS.

#define R_   384
#define P_   (R_ * R_)     // 147456 residue pairs
#define NBLK (P_ / 64)     // 2304 blocks, 64 pairs each

typedef __attribute__((ext_vector_type(8))) short  short8;   // 8 x bf16 MFMA frag
typedef __attribute__((ext_vector_type(4))) float  f32x4;    // MFMA accumulator

__device__ __forceinline__ unsigned short f2bf(float f) {
  unsigned u = __float_as_uint(f);
  unsigned r = ((u >> 16) & 1u) + 0x7FFFu;   // RNE
  return (unsigned short)((u + r) >> 16);
}
__device__ __forceinline__ float bf2f(unsigned short s) {
  return __uint_as_float(((unsigned)s) << 16);
}
// LDS layout for [p][c] tiles (p<64, c<256), bf16, pitch 256, XOR-swizzled in
// 16B blocks so both "lanes vary p" (attention) and MFMA A-frag reads avoid
// bank conflicts.
__device__ __forceinline__ int swz(int p, int c) {
  return p * 256 + ((((c >> 3) ^ (p & 31)) << 3) | (c & 7));
}

// ---- K0: fold weights into AbarT[n=256][i=128], MbarT[o=128][k=256] (bf16) ----
// AbarT[(h*64+j)][i] = 0.125 * sum_c Wq[i][h*64+c] * Wk[j][h*64+c]
// MbarT[o][(h*64+j)] =         sum_c Wv[j][h*64+c] * Wo[h*64+c][o]
__global__ void prep_kernel(const float* __restrict__ Wq, const float* __restrict__ Wk,
                            const float* __restrict__ Wv, const float* __restrict__ Wo,
                            unsigned short* __restrict__ AbarT,
                            unsigned short* __restrict__ MbarT) {
  int tid = blockIdx.x * blockDim.x + threadIdx.x;   // 65536 threads
  if (tid < 256 * 128) {
    int n = tid >> 7, i = tid & 127;
    int h = n >> 6, j = n & 63;
    const float* wq = Wq + i * 256 + h * 64;
    const float* wk = Wk + j * 256 + h * 64;
    float acc = 0.f;
#pragma unroll 8
    for (int c = 0; c < 64; ++c) acc += wq[c] * wk[c];
    AbarT[n * 128 + i] = f2bf(acc * 0.125f);         // 1/sqrt(64) folded in
  } else {
    int t2 = tid - 256 * 128;
    int o = t2 >> 8, k = t2 & 255;
    int h = k >> 6, j = k & 63;
    const float* wv = Wv + j * 256 + h * 64;
    const float* wo = Wo + (h * 64) * 128 + o;
    float acc = 0.f;
#pragma unroll 8
    for (int c = 0; c < 64; ++c) acc += wv[c] * wo[c * 128];
    MbarT[o * 256 + k] = f2bf(acc);
  }
}

// ---- main fused kernel: 64 pairs / block, 256 threads (4 waves) ----
__global__ __launch_bounds__(256, 2) void attn_kernel(
    const float* __restrict__ z2d, const float* __restrict__ t2d,
    const unsigned short* __restrict__ AbarT, const unsigned short* __restrict__ MbarT,
    const float* __restrict__ bo, float* __restrict__ out) {
  __shared__ __align__(16) unsigned short sT[64 * 256];  // tkv tile, bf16 swizzled
  __shared__ __align__(16) unsigned short sG[64 * 256];  // G then S, bf16 swizzled

  const int tid = threadIdx.x;
  const int P0  = blockIdx.x * 64;

  // ---- stage tkv (t2d[t][P0+p][j]) -> sT, fp32->bf16, swizzled ----
#pragma unroll
  for (int it = 0; it < 16; ++it) {
    int f  = it * 256 + tid;        // 4096 float4 total
    int t  = f >> 10;
    int rr = f & 1023;
    int p  = rr >> 4;
    int j4 = (rr & 15) << 2;
    const float4 v = *(const float4*)(t2d + (size_t)(t * P_ + P0 + p) * 64 + j4);
    ushort4 pk;
    pk.x = f2bf(v.x); pk.y = f2bf(v.y); pk.z = f2bf(v.z); pk.w = f2bf(v.w);
    *(ushort4*)(sT + swz(p, t * 64 + j4)) = pk;
  }
  // no barrier yet: sT/sG first read only after the post-GEMM1 barrier below

  const int wv_  = tid >> 6;   // wave id = GEMM1 m-tile
  const int lane = tid & 63;
  const int l = lane & 15;     // MFMA: A row / B col / D col
  const int q = lane >> 4;     // MFMA quad: k-group / D row-group

  // ---- GEMM1: G(64x256) = Z(64x128) @ Abar(128x256), bf16 MFMA ----
  f32x4 acc[16];
#pragma unroll
  for (int i = 0; i < 16; ++i) acc[i] = f32x4{0.f, 0.f, 0.f, 0.f};
  const float* zrow = z2d + (size_t)(P0 + wv_ * 16 + l) * 128;
#pragma unroll
  for (int kk = 0; kk < 4; ++kk) {
    float4 za = *(const float4*)(zrow + kk * 32 + q * 8);
    float4 zb = *(const float4*)(zrow + kk * 32 + q * 8 + 4);
    short8 af;
    af[0] = (short)f2bf(za.x); af[1] = (short)f2bf(za.y);
    af[2] = (short)f2bf(za.z); af[3] = (short)f2bf(za.w);
    af[4] = (short)f2bf(zb.x); af[5] = (short)f2bf(zb.y);
    af[6] = (short)f2bf(zb.z); af[7] = (short)f2bf(zb.w);
    const unsigned short* bbase = AbarT + l * 128 + kk * 32 + q * 8;
#pragma unroll
    for (int nt = 0; nt < 16; ++nt) {
      short8 bf = *(const short8*)(bbase + nt * 2048);   // n = nt*16 + l
      acc[nt] = __builtin_amdgcn_mfma_f32_16x16x32_bf16(af, bf, acc[nt], 0, 0, 0);
    }
  }
  // D[m=q*4+r][n=l] -> G[p = wv_*16+q*4+r][nt*16+l]  (m89-verified C/D layout)
#pragma unroll
  for (int nt = 0; nt < 16; ++nt) {
    int c = nt * 16 + l;
#pragma unroll
    for (int r = 0; r < 4; ++r) {
      int p = wv_ * 16 + q * 4 + r;
      sG[swz(p, c)] = f2bf(acc[nt][r]);
    }
  }
  __syncthreads();

  // ---- attention: thread = (pair p, head h); logits over T=4, softmax, S ----
  {
    const int p = tid & 63;
    const int h = tid >> 6;
    float lg0 = 0.f, lg1 = 0.f, lg2 = 0.f, lg3 = 0.f;
#pragma unroll
    for (int jb = 0; jb < 64; jb += 4) {
      ushort4 g4 = *(const ushort4*)(sG + swz(p, h * 64 + jb));
      float g0 = bf2f(g4.x), g1 = bf2f(g4.y), g2 = bf2f(g4.z), g3 = bf2f(g4.w);
      ushort4 k0 = *(const ushort4*)(sT + swz(p, jb));
      ushort4 k1 = *(const ushort4*)(sT + swz(p, 64 + jb));
      ushort4 k2 = *(const ushort4*)(sT + swz(p, 128 + jb));
      ushort4 k3 = *(const ushort4*)(sT + swz(p, 192 + jb));
      lg0 += g0 * bf2f(k0.x) + g1 * bf2f(k0.y) + g2 * bf2f(k0.z) + g3 * bf2f(k0.w);
      lg1 += g0 * bf2f(k1.x) + g1 * bf2f(k1.y) + g2 * bf2f(k1.z) + g3 * bf2f(k1.w);
      lg2 += g0 * bf2f(k2.x) + g1 * bf2f(k2.y) + g2 * bf2f(k2.z) + g3 * bf2f(k2.w);
      lg3 += g0 * bf2f(k3.x) + g1 * bf2f(k3.y) + g2 * bf2f(k3.z) + g3 * bf2f(k3.w);
    }
    float mx = fmaxf(fmaxf(lg0, lg1), fmaxf(lg2, lg3));
    float e0 = __expf(lg0 - mx), e1 = __expf(lg1 - mx);
    float e2 = __expf(lg2 - mx), e3 = __expf(lg3 - mx);
    float inv = 1.f / (e0 + e1 + e2 + e3);
    e0 *= inv; e1 *= inv; e2 *= inv; e3 *= inv;
    // S[p][h*64+j] = sum_t w_t * tkv[p][t][j]; in-place over G (this thread's
    // own slice only, already consumed)
#pragma unroll
    for (int jb = 0; jb < 64; jb += 4) {
      ushort4 k0 = *(const ushort4*)(sT + swz(p, jb));
      ushort4 k1 = *(const ushort4*)(sT + swz(p, 64 + jb));
      ushort4 k2 = *(const ushort4*)(sT + swz(p, 128 + jb));
      ushort4 k3 = *(const ushort4*)(sT + swz(p, 192 + jb));
      ushort4 sv;
      sv.x = f2bf(e0 * bf2f(k0.x) + e1 * bf2f(k1.x) + e2 * bf2f(k2.x) + e3 * bf2f(k3.x));
      sv.y = f2bf(e0 * bf2f(k0.y) + e1 * bf2f(k1.y) + e2 * bf2f(k2.y) + e3 * bf2f(k3.y));
      sv.z = f2bf(e0 * bf2f(k0.z) + e1 * bf2f(k1.z) + e2 * bf2f(k2.z) + e3 * bf2f(k3.z));
      sv.w = f2bf(e0 * bf2f(k0.w) + e1 * bf2f(k1.w) + e2 * bf2f(k2.w) + e3 * bf2f(k3.w));
      *(ushort4*)(sG + swz(p, h * 64 + jb)) = sv;
    }
  }
  __syncthreads();

  // ---- GEMM2: OUT(64x128) = S(64x256) @ Mbar(256x128) + bo ----
  // wave -> n0 = 32*wv_ (2 n-tiles), all 4 m-tiles
  f32x4 acc2[4][2];
#pragma unroll
  for (int mt = 0; mt < 4; ++mt) {
    acc2[mt][0] = f32x4{0.f, 0.f, 0.f, 0.f};
    acc2[mt][1] = f32x4{0.f, 0.f, 0.f, 0.f};
  }
#pragma unroll
  for (int kk = 0; kk < 8; ++kk) {
    const unsigned short* mb = MbarT + (size_t)(wv_ * 32 + l) * 256 + kk * 32 + q * 8;
    short8 b0 = *(const short8*)(mb);
    short8 b1 = *(const short8*)(mb + 16 * 256);
#pragma unroll
    for (int mt = 0; mt < 4; ++mt) {
      const int p  = mt * 16 + l;
      const int cb = kk * 32 + q * 8;          // cb % 8 == 0 -> one 16B block
      short8 af2 = *(const short8*)(sG + p * 256 + (((cb >> 3) ^ (p & 31)) << 3));
      acc2[mt][0] = __builtin_amdgcn_mfma_f32_16x16x32_bf16(af2, b0, acc2[mt][0], 0, 0, 0);
      acc2[mt][1] = __builtin_amdgcn_mfma_f32_16x16x32_bf16(af2, b1, acc2[mt][1], 0, 0, 0);
    }
  }
  const float bo0 = bo[wv_ * 32 + l];
  const float bo1 = bo[wv_ * 32 + 16 + l];
#pragma unroll
  for (int mt = 0; mt < 4; ++mt) {
#pragma unroll
    for (int r = 0; r < 4; ++r) {
      size_t row = (size_t)(P0 + mt * 16 + q * 4 + r);
      out[row * 128 + wv_ * 32 + l]      = acc2[mt][0][r] + bo0;
      out[row * 128 + wv_ * 32 + 16 + l] = acc2[mt][1][r] + bo1;
    }
  }
}

extern "C" void kernel_launch(void* const* d_in, const int* in_sizes, int n_in,
                              void* d_out, int out_size, void* d_ws, size_t ws_size,
                              hipStream_t stream) {
  const float* z2d = (const float*)d_in[0];
  const float* t2d = (const float*)d_in[1];
  const float* Wq  = (const float*)d_in[2];
  const float* Wk  = (const float*)d_in[3];
  const float* Wv  = (const float*)d_in[4];
  const float* Wo  = (const float*)d_in[5];
  const float* bo  = (const float*)d_in[6];

  unsigned short* AbarT = (unsigned short*)d_ws;           // 256*128 bf16 = 64 KB
  unsigned short* MbarT = AbarT + 256 * 128;               // 128*256 bf16 = 64 KB
  float* out = (float*)d_out;

  hipLaunchKernelGGL(prep_kernel, dim3(256), dim3(256), 0, stream,
                     Wq, Wk, Wv, Wo, AbarT, MbarT);
  hipLaunchKernelGGL(attn_kernel, dim3(NBLK), dim3(256), 0, stream,
                     z2d, t2d, AbarT, MbarT, bo, out);
}